// Round 11
// baseline (177.036 us; speedup 1.0000x reference)
//
#include <hip/hip_runtime.h>

#define NN 50000
#define NE 800000
#define NB 64
#define DIM 64
#define TM 128
#define CAP 64    // per-node CSR capacity. deg ~ Poisson(16), max over 50k ~40.

typedef float vfloat4 __attribute__((ext_vector_type(4)));

// ws layout: cursor[NN] | cursor2[NN] | eids[NN*CAP] | U1[NB*DIM f32] | ve[NN*DIM f32] | posdump[NE]

__global__ __launch_bounds__(256) void zero_k(int4* __restrict__ p, int n4) {
    int i = blockIdx.x * 256 + threadIdx.x;
    if (i < n4) p[i] = make_int4(0, 0, 0, 0);
}

// PROBE: replicates fill's src-load + with-return atomic, but stores COALESCED.
// T11 - T10 = this kernel + g  ->  isolates atomic machinery vs scattered store.
__global__ __launch_bounds__(256) void fillB_k(const int* __restrict__ src,
                                               int* __restrict__ cursor2,
                                               int* __restrict__ posdump) {
    int t = blockIdx.x * 256 + threadIdx.x;   // grid exactly NE threads
    if (t < NE) {
        int s = src[t];
        int pos = atomicAdd(&cursor2[s], 1);
        posdump[t] = pos;                     // coalesced store
    }
}

// one edge per thread; nontemporal eids store (same as round 10);
// blocks 0..63 also premix U1 = u@W1u + b1
__global__ __launch_bounds__(256) void fill_k(const int* __restrict__ src,
                                              int* __restrict__ cursor,
                                              int* __restrict__ eids,
                                              const float* __restrict__ u,
                                              const float* __restrict__ W1,
                                              const float* __restrict__ b1,
                                              float* __restrict__ U1) {
    int t = blockIdx.x * 256 + threadIdx.x;   // grid exactly NE threads
    if (t < NE) {
        int s = src[t];
        int pos = atomicAdd(&cursor[s], 1);
        __builtin_nontemporal_store(t, &eids[s * CAP + pos]);
    }
    if (blockIdx.x < NB && threadIdx.x < DIM) {
        int b = blockIdx.x, jj = threadIdx.x;
        float a = b1[jj];
        const float* up = u + b * DIM;
        #pragma unroll 8
        for (int k = 0; k < DIM; ++k)
            a = fmaf(up[k], W1[(2 * DIM + k) * DIM + jj], a);
        U1[b * DIM + jj] = a;
    }
}

// one wave per node; 4 edge slots x 16 float4 chunks; unconditional clamped gathers.
__global__ __launch_bounds__(256) void reduce_k(const int* __restrict__ deg_arr,
                                                const int* __restrict__ eids,
                                                const vfloat4* __restrict__ ea4,
                                                float4* __restrict__ ve4) {
    int n = (blockIdx.x * 256 + threadIdx.x) >> 6;   // grid exactly NN*64 threads
    int lane = threadIdx.x & 63;
    int chunk = lane & 15, slot = lane >> 4;
    int deg = deg_arr[n];
    const int* ebase = eids + (size_t)n * CAP;

    vfloat4 acc = {0.f, 0.f, 0.f, 0.f};
    const vfloat4 vzero = {0.f, 0.f, 0.f, 0.f};

    if (deg > 0) {
        int dm1 = deg - 1;
        int e[8];
        #pragma unroll
        for (int r = 0; r < 8; ++r) {
            int j = slot + r * 4;
            e[r] = ebase[j < dm1 ? j : dm1];
        }
        #pragma unroll
        for (int r = 0; r < 8; ++r) {
            vfloat4 v = __builtin_nontemporal_load(&ea4[(size_t)e[r] * 16 + chunk]);
            acc += (slot + r * 4 < deg) ? v : vzero;
        }
        for (int j = 32 + slot; j < deg; j += 4) {   // rare tail: 32 < deg <= CAP
            int ee = ebase[j];
            vfloat4 v = __builtin_nontemporal_load(&ea4[(size_t)ee * 16 + chunk]);
            acc += v;
        }
    }

    #pragma unroll
    for (int m = 16; m <= 32; m <<= 1) {
        acc.x += __shfl_xor(acc.x, m, 64);
        acc.y += __shfl_xor(acc.y, m, 64);
        acc.z += __shfl_xor(acc.z, m, 64);
        acc.w += __shfl_xor(acc.w, m, 64);
    }
    if (slot == 0) {
        float rs = 1.0f / fmaxf((float)deg, 1.0f);
        ve4[(size_t)n * 16 + chunk] = make_float4(acc.x * rs, acc.y * rs, acc.z * rs, acc.w * rs);
    }
}

#define LDA 132  // padded row stride for A tile

// each thread computes 4 nodes x 4 dims
__device__ __forceinline__ void gemm4(float acc[4][4],
                                      const float* __restrict__ A,
                                      const float* __restrict__ Wb,
                                      int NG, int DG) {
    #pragma unroll 4
    for (int k = 0; k < 64; ++k) {
        const float4 w = *(const float4*)&Wb[k * 64 + DG];
        const float4 a = *(const float4*)&A[k * LDA + NG];
        const float av[4] = {a.x, a.y, a.z, a.w};
        const float wv[4] = {w.x, w.y, w.z, w.w};
        #pragma unroll
        for (int i = 0; i < 4; ++i)
            #pragma unroll
            for (int j = 0; j < 4; ++j)
                acc[i][j] = fmaf(av[i], wv[j], acc[i][j]);
    }
}

__global__ __launch_bounds__(512) void mlp_k(const float* __restrict__ x,
                                             const int* __restrict__ batch,
                                             const float* __restrict__ W1,
                                             const float* __restrict__ W2,
                                             const float* __restrict__ b2,
                                             const float* __restrict__ ve,
                                             const float* __restrict__ U1,
                                             float* __restrict__ out) {
    __shared__ float A[64 * LDA];
    __shared__ float Wb[64 * 64];

    const int t = threadIdx.x;        // 0..511
    const int c = t & 15;             // staging k-chunk
    const int rb = t >> 4;            // 0..31
    const int DG = (t & 15) * 4;      // 4 output dims
    const int NG = (t >> 4) * 4;      // 4 local nodes
    const int n0 = blockIdx.x * TM;

    float acc[4][4];

    #pragma unroll
    for (int i = 0; i < 4; ++i) {
        int n = n0 + NG + i;
        int b = (n < NN) ? batch[n] : 0;
        const float4 uv = *(const float4*)&U1[b * DIM + DG];
        acc[i][0] = uv.x; acc[i][1] = uv.y; acc[i][2] = uv.z; acc[i][3] = uv.w;
    }

    // ---------- pass 1: x @ W1[0:64] ----------
    #pragma unroll
    for (int it = 0; it < 4; ++it) {
        int r = rb + it * 32;
        int n = n0 + r;
        float4 v = make_float4(0.f, 0.f, 0.f, 0.f);
        if (n < NN) v = *(const float4*)&x[(size_t)n * DIM + c * 4];
        A[(c * 4 + 0) * LDA + r] = v.x;
        A[(c * 4 + 1) * LDA + r] = v.y;
        A[(c * 4 + 2) * LDA + r] = v.z;
        A[(c * 4 + 3) * LDA + r] = v.w;
    }
    #pragma unroll
    for (int it = 0; it < 2; ++it) {
        int r = rb + it * 32;
        *(float4*)&Wb[r * 64 + c * 4] = *(const float4*)&W1[(size_t)r * DIM + c * 4];
    }
    __syncthreads();
    gemm4(acc, A, Wb, NG, DG);
    __syncthreads();

    // ---------- pass 2: v_e @ W1[64:128] ----------
    #pragma unroll
    for (int it = 0; it < 4; ++it) {
        int r = rb + it * 32;
        int n = n0 + r;
        float4 v = make_float4(0.f, 0.f, 0.f, 0.f);
        if (n < NN) v = *(const float4*)&ve[(size_t)n * DIM + c * 4];
        A[(c * 4 + 0) * LDA + r] = v.x;
        A[(c * 4 + 1) * LDA + r] = v.y;
        A[(c * 4 + 2) * LDA + r] = v.z;
        A[(c * 4 + 3) * LDA + r] = v.w;
    }
    #pragma unroll
    for (int it = 0; it < 2; ++it) {
        int r = rb + it * 32;
        *(float4*)&Wb[r * 64 + c * 4] = *(const float4*)&W1[(size_t)(64 + r) * DIM + c * 4];
    }
    __syncthreads();
    gemm4(acc, A, Wb, NG, DG);

    #pragma unroll
    for (int i = 0; i < 4; ++i)
        #pragma unroll
        for (int j = 0; j < 4; ++j)
            acc[i][j] = fmaxf(acc[i][j], 0.f);

    __syncthreads();

    // ---------- layer 2: h @ W2 ----------
    #pragma unroll
    for (int j = 0; j < 4; ++j) {
        float4 h = make_float4(acc[0][j], acc[1][j], acc[2][j], acc[3][j]);
        *(float4*)&A[(DG + j) * LDA + NG] = h;
    }
    #pragma unroll
    for (int it = 0; it < 2; ++it) {
        int r = rb + it * 32;
        *(float4*)&Wb[r * 64 + c * 4] = *(const float4*)&W2[(size_t)r * DIM + c * 4];
    }
    __syncthreads();

    {
        const float4 bv = *(const float4*)&b2[DG];
        #pragma unroll
        for (int i = 0; i < 4; ++i) {
            acc[i][0] = bv.x; acc[i][1] = bv.y; acc[i][2] = bv.z; acc[i][3] = bv.w;
        }
    }
    gemm4(acc, A, Wb, NG, DG);

    #pragma unroll
    for (int i = 0; i < 4; ++i) {
        int n = n0 + NG + i;
        if (n < NN) {
            float4 o = make_float4(acc[i][0], acc[i][1], acc[i][2], acc[i][3]);
            *(float4*)&out[(size_t)n * DIM + DG] = o;
        }
    }
}

extern "C" void kernel_launch(void* const* d_in, const int* in_sizes, int n_in,
                              void* d_out, int out_size, void* d_ws, size_t ws_size,
                              hipStream_t stream)
{
    const float* x     = (const float*)d_in[0];
    const int*   eidx  = (const int*)d_in[1];    // [2,E], row 0 = src
    const float* ea    = (const float*)d_in[2];
    const float* u     = (const float*)d_in[3];
    const int*   batch = (const int*)d_in[4];
    const float* W1    = (const float*)d_in[5];
    const float* b1    = (const float*)d_in[6];
    const float* W2    = (const float*)d_in[7];
    const float* b2    = (const float*)d_in[8];
    float* out = (float*)d_out;

    int*   cursor  = (int*)d_ws;                        // NN ints (becomes deg)
    int*   cursor2 = cursor + NN;                       // NN ints (probe)
    int*   eids    = cursor2 + NN;                      // NN*CAP ints
    float* U1      = (float*)(eids + (size_t)NN * CAP); // NB*DIM floats
    float* ve      = U1 + NB * DIM;                     // NN*DIM floats
    int*   posdump = (int*)(ve + (size_t)NN * DIM);     // NE ints (probe)

    // zero cursor AND cursor2 (2*NN ints = 400KB)
    zero_k<<<(2 * NN / 4 + 255) / 256, 256, 0, stream>>>((int4*)cursor, 2 * NN / 4);
    // PROBE (additive; writes only cursor2/posdump)
    fillB_k<<<NE / 256, 256, 0, stream>>>(eidx, cursor2, posdump);
    fill_k<<<NE / 256, 256, 0, stream>>>(eidx, cursor, eids, u, W1, b1, U1);
    reduce_k<<<(NN * 64) / 256, 256, 0, stream>>>(cursor, eids, (const vfloat4*)ea, (float4*)ve);
    mlp_k<<<(NN + TM - 1) / TM, 512, 0, stream>>>(x, batch, W1, W2, b2, ve, U1, out);
}

// Round 12
// 93.635 us; speedup vs baseline: 1.8907x; 1.8907x over previous
//
#include <hip/hip_runtime.h>

#define NN 50000
#define NE 800000
#define NB 64
#define DIM 64
#define TM 128
#define CAP 64        // per-node CSR capacity; max deg ~40
#define EB 4096       // edges per bucketA block
#define NBLK_A 196    // ceil(NE/EB): 195*4096+1280 = 800000
#define NBKT 196      // buckets of 256 nodes: (50000+255)/256

typedef float vfloat4 __attribute__((ext_vector_type(4)));

// ws: deg[NN] | eids[NN*CAP] | U1[NB*DIM f32] | ve[NN*DIM f32] | bbuf[NBLK_A*EB] | blkoff[NBLK_A*(NBKT+1)]

// Pass A: per-block LDS counting-sort of 4096 edges by bucket (s>>8).
// Coalesced writes; NO global atomics. blocks 0..63 also premix U1.
__global__ __launch_bounds__(1024) void bucketA_k(const int* __restrict__ src,
                                                  int* __restrict__ bbuf,
                                                  int* __restrict__ blkoff,
                                                  const float* __restrict__ u,
                                                  const float* __restrict__ W1,
                                                  const float* __restrict__ b1,
                                                  float* __restrict__ U1) {
    __shared__ int hist[NBKT];
    __shared__ int cnt2[NBKT];
    __shared__ int off[NBKT + 1];
    __shared__ int sortedE[EB];

    const int tid = threadIdx.x;
    const int blk = blockIdx.x;

    for (int i = tid; i < NBKT; i += 1024) { hist[i] = 0; cnt2[i] = 0; }
    __syncthreads();

    const int e0 = (blk * 1024 + tid) * 4;
    const bool valid = (e0 < NE);                 // NE%4==0 -> whole int4 valid or none
    int4 s4 = make_int4(0, 0, 0, 0);
    if (valid) s4 = ((const int4*)src)[e0 >> 2];
    const int bk0 = s4.x >> 8, bk1 = s4.y >> 8, bk2 = s4.z >> 8, bk3 = s4.w >> 8;

    if (valid) {
        atomicAdd(&hist[bk0], 1);
        atomicAdd(&hist[bk1], 1);
        atomicAdd(&hist[bk2], 1);
        atomicAdd(&hist[bk3], 1);
    }
    __syncthreads();

    // exclusive scan of hist[196] by wave 0 (196 = 49*4)
    if (tid < 64) {
        const int base = tid * 4;
        int a0 = 0, a1 = 0, a2 = 0, a3 = 0;
        if (base < NBKT) {
            a0 = hist[base + 0]; a1 = hist[base + 1];
            a2 = hist[base + 2]; a3 = hist[base + 3];
        }
        const int sum = a0 + a1 + a2 + a3;
        int run = sum;
        #pragma unroll
        for (int m = 1; m < 64; m <<= 1) {
            int v = __shfl_up(run, m, 64);
            if (tid >= m) run += v;
        }
        const int excl = run - sum;
        if (base < NBKT) {
            off[base + 0] = excl;
            off[base + 1] = excl + a0;
            off[base + 2] = excl + a0 + a1;
            off[base + 3] = excl + a0 + a1 + a2;
        }
        if (tid == 63) off[NBKT] = run;           // block's edge count
    }
    __syncthreads();

    if (valid) {
        int r0 = off[bk0] + atomicAdd(&cnt2[bk0], 1); sortedE[r0] = e0 + 0;
        int r1 = off[bk1] + atomicAdd(&cnt2[bk1], 1); sortedE[r1] = e0 + 1;
        int r2 = off[bk2] + atomicAdd(&cnt2[bk2], 1); sortedE[r2] = e0 + 2;
        int r3 = off[bk3] + atomicAdd(&cnt2[bk3], 1); sortedE[r3] = e0 + 3;
    }
    __syncthreads();

    const int nE = min(EB, NE - blk * EB);
    for (int i = tid; i < nE; i += 1024)
        bbuf[blk * EB + i] = sortedE[i];
    for (int i = tid; i <= NBKT; i += 1024)
        blkoff[blk * (NBKT + 1) + i] = off[i];

    // premix U1 (same as before)
    if (blk < NB && tid < DIM) {
        float a = b1[tid];
        const float* up = u + blk * DIM;
        #pragma unroll 8
        for (int k = 0; k < DIM; ++k)
            a = fmaf(up[k], W1[(2 * DIM + k) * DIM + tid], a);
        U1[blk * DIM + tid] = a;
    }
}

// Pass B: one block per bucket. Flatten the 196 segments, rank each edge with an
// LDS atomic over 256 node counters, place into eids; write deg directly.
__global__ __launch_bounds__(1024) void placeB_k(const int* __restrict__ src,
                                                 const int* __restrict__ bbuf,
                                                 const int* __restrict__ blkoff,
                                                 int* __restrict__ eids,
                                                 int* __restrict__ deg) {
    __shared__ int cnt[256];
    __shared__ int lo_s[NBLK_A], hi_s[NBLK_A];
    __shared__ int segoff[NBLK_A + 1];

    const int b = blockIdx.x;
    const int tid = threadIdx.x;

    if (tid < 256) cnt[tid] = 0;
    if (tid < NBLK_A) {
        lo_s[tid] = blkoff[tid * (NBKT + 1) + b];
        hi_s[tid] = blkoff[tid * (NBKT + 1) + b + 1];
    }
    __syncthreads();

    // exclusive scan of segment lengths (196 = 49*4) by wave 0
    if (tid < 64) {
        const int base = tid * 4;
        int a0 = 0, a1 = 0, a2 = 0, a3 = 0;
        if (base < NBLK_A) {
            a0 = hi_s[base + 0] - lo_s[base + 0];
            a1 = hi_s[base + 1] - lo_s[base + 1];
            a2 = hi_s[base + 2] - lo_s[base + 2];
            a3 = hi_s[base + 3] - lo_s[base + 3];
        }
        const int sum = a0 + a1 + a2 + a3;
        int run = sum;
        #pragma unroll
        for (int m = 1; m < 64; m <<= 1) {
            int v = __shfl_up(run, m, 64);
            if (tid >= m) run += v;
        }
        const int excl = run - sum;
        if (base < NBLK_A) {
            segoff[base + 0] = excl;
            segoff[base + 1] = excl + a0;
            segoff[base + 2] = excl + a0 + a1;
            segoff[base + 3] = excl + a0 + a1 + a2;
        }
        if (tid == 63) segoff[NBLK_A] = run;
    }
    __syncthreads();

    const int total = segoff[NBLK_A];
    for (int i = tid; i < total; i += 1024) {
        // find blk: segoff[blk] <= i < segoff[blk+1]
        int lo2 = 0, hi2 = NBLK_A;
        while (lo2 + 1 < hi2) {
            int mid = (lo2 + hi2) >> 1;
            if (segoff[mid] <= i) lo2 = mid; else hi2 = mid;
        }
        const int blk = lo2;
        const int idx = i - segoff[blk] + lo_s[blk];
        const int e = bbuf[blk * EB + idx];
        const int s = src[e];
        const int rank = atomicAdd(&cnt[s & 255], 1);
        eids[s * CAP + rank] = e;
    }
    __syncthreads();

    const int s = b * 256 + tid;
    if (tid < 256 && s < NN) deg[s] = cnt[tid];
}

// one wave per node; 4 edge slots x 16 float4 chunks; unconditional clamped gathers.
__global__ __launch_bounds__(256) void reduce_k(const int* __restrict__ deg_arr,
                                                const int* __restrict__ eids,
                                                const vfloat4* __restrict__ ea4,
                                                float4* __restrict__ ve4) {
    int n = (blockIdx.x * 256 + threadIdx.x) >> 6;   // grid exactly NN*64 threads
    int lane = threadIdx.x & 63;
    int chunk = lane & 15, slot = lane >> 4;
    int deg = deg_arr[n];
    const int* ebase = eids + (size_t)n * CAP;

    vfloat4 acc = {0.f, 0.f, 0.f, 0.f};
    const vfloat4 vzero = {0.f, 0.f, 0.f, 0.f};

    if (deg > 0) {
        int dm1 = deg - 1;
        int e[8];
        #pragma unroll
        for (int r = 0; r < 8; ++r) {
            int j = slot + r * 4;
            e[r] = ebase[j < dm1 ? j : dm1];
        }
        #pragma unroll
        for (int r = 0; r < 8; ++r) {
            vfloat4 v = __builtin_nontemporal_load(&ea4[(size_t)e[r] * 16 + chunk]);
            acc += (slot + r * 4 < deg) ? v : vzero;
        }
        for (int j = 32 + slot; j < deg; j += 4) {   // rare tail: 32 < deg <= CAP
            int ee = ebase[j];
            vfloat4 v = __builtin_nontemporal_load(&ea4[(size_t)ee * 16 + chunk]);
            acc += v;
        }
    }

    #pragma unroll
    for (int m = 16; m <= 32; m <<= 1) {
        acc.x += __shfl_xor(acc.x, m, 64);
        acc.y += __shfl_xor(acc.y, m, 64);
        acc.z += __shfl_xor(acc.z, m, 64);
        acc.w += __shfl_xor(acc.w, m, 64);
    }
    if (slot == 0) {
        float rs = 1.0f / fmaxf((float)deg, 1.0f);
        ve4[(size_t)n * 16 + chunk] = make_float4(acc.x * rs, acc.y * rs, acc.z * rs, acc.w * rs);
    }
}

#define LDA 132  // padded row stride for A tile

// each thread computes 4 nodes x 4 dims
__device__ __forceinline__ void gemm4(float acc[4][4],
                                      const float* __restrict__ A,
                                      const float* __restrict__ Wb,
                                      int NG, int DG) {
    #pragma unroll 4
    for (int k = 0; k < 64; ++k) {
        const float4 w = *(const float4*)&Wb[k * 64 + DG];
        const float4 a = *(const float4*)&A[k * LDA + NG];
        const float av[4] = {a.x, a.y, a.z, a.w};
        const float wv[4] = {w.x, w.y, w.z, w.w};
        #pragma unroll
        for (int i = 0; i < 4; ++i)
            #pragma unroll
            for (int j = 0; j < 4; ++j)
                acc[i][j] = fmaf(av[i], wv[j], acc[i][j]);
    }
}

__global__ __launch_bounds__(512) void mlp_k(const float* __restrict__ x,
                                             const int* __restrict__ batch,
                                             const float* __restrict__ W1,
                                             const float* __restrict__ W2,
                                             const float* __restrict__ b2,
                                             const float* __restrict__ ve,
                                             const float* __restrict__ U1,
                                             float* __restrict__ out) {
    __shared__ float A[64 * LDA];
    __shared__ float Wb[64 * 64];

    const int t = threadIdx.x;        // 0..511
    const int c = t & 15;             // staging k-chunk
    const int rb = t >> 4;            // 0..31
    const int DG = (t & 15) * 4;      // 4 output dims
    const int NG = (t >> 4) * 4;      // 4 local nodes
    const int n0 = blockIdx.x * TM;

    float acc[4][4];

    #pragma unroll
    for (int i = 0; i < 4; ++i) {
        int n = n0 + NG + i;
        int b = (n < NN) ? batch[n] : 0;
        const float4 uv = *(const float4*)&U1[b * DIM + DG];
        acc[i][0] = uv.x; acc[i][1] = uv.y; acc[i][2] = uv.z; acc[i][3] = uv.w;
    }

    // ---------- pass 1: x @ W1[0:64] ----------
    #pragma unroll
    for (int it = 0; it < 4; ++it) {
        int r = rb + it * 32;
        int n = n0 + r;
        float4 v = make_float4(0.f, 0.f, 0.f, 0.f);
        if (n < NN) v = *(const float4*)&x[(size_t)n * DIM + c * 4];
        A[(c * 4 + 0) * LDA + r] = v.x;
        A[(c * 4 + 1) * LDA + r] = v.y;
        A[(c * 4 + 2) * LDA + r] = v.z;
        A[(c * 4 + 3) * LDA + r] = v.w;
    }
    #pragma unroll
    for (int it = 0; it < 2; ++it) {
        int r = rb + it * 32;
        *(float4*)&Wb[r * 64 + c * 4] = *(const float4*)&W1[(size_t)r * DIM + c * 4];
    }
    __syncthreads();
    gemm4(acc, A, Wb, NG, DG);
    __syncthreads();

    // ---------- pass 2: v_e @ W1[64:128] ----------
    #pragma unroll
    for (int it = 0; it < 4; ++it) {
        int r = rb + it * 32;
        int n = n0 + r;
        float4 v = make_float4(0.f, 0.f, 0.f, 0.f);
        if (n < NN) v = *(const float4*)&ve[(size_t)n * DIM + c * 4];
        A[(c * 4 + 0) * LDA + r] = v.x;
        A[(c * 4 + 1) * LDA + r] = v.y;
        A[(c * 4 + 2) * LDA + r] = v.z;
        A[(c * 4 + 3) * LDA + r] = v.w;
    }
    #pragma unroll
    for (int it = 0; it < 2; ++it) {
        int r = rb + it * 32;
        *(float4*)&Wb[r * 64 + c * 4] = *(const float4*)&W1[(size_t)(64 + r) * DIM + c * 4];
    }
    __syncthreads();
    gemm4(acc, A, Wb, NG, DG);

    #pragma unroll
    for (int i = 0; i < 4; ++i)
        #pragma unroll
        for (int j = 0; j < 4; ++j)
            acc[i][j] = fmaxf(acc[i][j], 0.f);

    __syncthreads();

    // ---------- layer 2: h @ W2 ----------
    #pragma unroll
    for (int j = 0; j < 4; ++j) {
        float4 h = make_float4(acc[0][j], acc[1][j], acc[2][j], acc[3][j]);
        *(float4*)&A[(DG + j) * LDA + NG] = h;
    }
    #pragma unroll
    for (int it = 0; it < 2; ++it) {
        int r = rb + it * 32;
        *(float4*)&Wb[r * 64 + c * 4] = *(const float4*)&W2[(size_t)r * DIM + c * 4];
    }
    __syncthreads();

    {
        const float4 bv = *(const float4*)&b2[DG];
        #pragma unroll
        for (int i = 0; i < 4; ++i) {
            acc[i][0] = bv.x; acc[i][1] = bv.y; acc[i][2] = bv.z; acc[i][3] = bv.w;
        }
    }
    gemm4(acc, A, Wb, NG, DG);

    #pragma unroll
    for (int i = 0; i < 4; ++i) {
        int n = n0 + NG + i;
        if (n < NN) {
            float4 o = make_float4(acc[i][0], acc[i][1], acc[i][2], acc[i][3]);
            *(float4*)&out[(size_t)n * DIM + DG] = o;
        }
    }
}

extern "C" void kernel_launch(void* const* d_in, const int* in_sizes, int n_in,
                              void* d_out, int out_size, void* d_ws, size_t ws_size,
                              hipStream_t stream)
{
    const float* x     = (const float*)d_in[0];
    const int*   eidx  = (const int*)d_in[1];    // [2,E], row 0 = src
    const float* ea    = (const float*)d_in[2];
    const float* u     = (const float*)d_in[3];
    const int*   batch = (const int*)d_in[4];
    const float* W1    = (const float*)d_in[5];
    const float* b1    = (const float*)d_in[6];
    const float* W2    = (const float*)d_in[7];
    const float* b2    = (const float*)d_in[8];
    float* out = (float*)d_out;

    int*   deg    = (int*)d_ws;                        // NN ints
    int*   eids   = deg + NN;                          // NN*CAP ints
    float* U1     = (float*)(eids + (size_t)NN * CAP); // NB*DIM floats
    float* ve     = U1 + NB * DIM;                     // NN*DIM floats
    int*   bbuf   = (int*)(ve + (size_t)NN * DIM);     // NBLK_A*EB ints
    int*   blkoff = bbuf + (size_t)NBLK_A * EB;        // NBLK_A*(NBKT+1) ints

    bucketA_k<<<NBLK_A, 1024, 0, stream>>>(eidx, bbuf, blkoff, u, W1, b1, U1);
    placeB_k<<<NBKT, 1024, 0, stream>>>(eidx, bbuf, blkoff, eids, deg);
    reduce_k<<<(NN * 64) / 256, 256, 0, stream>>>(deg, eids, (const vfloat4*)ea, (float4*)ve);
    mlp_k<<<(NN + TM - 1) / TM, 512, 0, stream>>>(x, batch, W1, W2, b2, ve, U1, out);
}